// Round 1
// baseline (169.101 us; speedup 1.0000x reference)
//
#include <hip/hip_runtime.h>
#include <math.h>

// eDCC loss: reference reads only projs[0,127,:,:] and projs[0,29,:,:].
// For each l in [0,1024): P_i[l] = sum_s projs[127,l,s]*w[s],
//                         P_j[l] = sum_s projs[29 ,l,s]*w[s],
// w[s] = exp(sigma * s_grid[s] * SPACING), sigma = 0.013*tan(pi*98/128),
// s_grid[s] = (s - 127.5)*SPACING.
// out = sum_l (2/128)*|P_i - P_j|/(P_i + P_j)   (den != 0 guard), B=1 mean.

#define NPROJS   128
#define L_ROWS   1024
#define S_LEN    256
#define I_ROW    127
#define J_ROW    29

__global__ __launch_bounds__(256) void edcc_kernel(const float* __restrict__ projs,
                                                   float* __restrict__ out) {
    const int gwave = (blockIdx.x * blockDim.x + threadIdx.x) >> 6;  // one wave per l-row
    const int lane  = threadIdx.x & 63;
    if (gwave >= L_ROWS) return;
    const int l = gwave;

    // Constants in double, cast late (error analysis: <<1e-3 on final sum).
    const double sigma = 0.013 * tan((98.0 * (6.283185307179586 / 128.0)) * 0.5);

    const float* rowi = projs + ((size_t)(I_ROW * L_ROWS + l)) * S_LEN;
    const float* rowj = projs + ((size_t)(J_ROW * L_ROWS + l)) * S_LEN;

    // lane covers s-indices [lane*4, lane*4+4): one float4 per row, coalesced.
    const float4 vi = *reinterpret_cast<const float4*>(rowi + lane * 4);
    const float4 vj = *reinterpret_cast<const float4*>(rowj + lane * 4);
    const float ai[4] = {vi.x, vi.y, vi.z, vi.w};
    const float bj[4] = {vj.x, vj.y, vj.z, vj.w};

    float pi_sum = 0.0f, pj_sum = 0.0f;
#pragma unroll
    for (int c = 0; c < 4; ++c) {
        const int k = lane * 4 + c;
        const double s_k = ((double)k - 127.5) * 4.7952;       // linspace grid
        const float  w   = expf((float)(sigma * s_k * 4.7952)); // |arg| <= 34.6
        pi_sum = fmaf(ai[c], w, pi_sum);
        pj_sum = fmaf(bj[c], w, pj_sum);
    }

    // wave64 butterfly reduction of both sums
#pragma unroll
    for (int off = 32; off > 0; off >>= 1) {
        pi_sum += __shfl_xor(pi_sum, off);
        pj_sum += __shfl_xor(pj_sum, off);
    }

    if (lane == 0) {
        const float den  = pi_sum + pj_sum;
        const float term = (den != 0.0f)
                             ? (2.0f / (float)NPROJS) * fabsf(pi_sum - pj_sum) / den
                             : 0.0f;
        atomicAdd(out, term);  // 1024 atomics to one address — negligible
    }
}

extern "C" void kernel_launch(void* const* d_in, const int* in_sizes, int n_in,
                              void* d_out, int out_size, void* d_ws, size_t ws_size,
                              hipStream_t stream) {
    const float* projs = (const float*)d_in[0];
    float* out = (float*)d_out;

    // d_out is re-poisoned to 0xAA before every timed launch — zero it.
    hipMemsetAsync(out, 0, sizeof(float) * (size_t)out_size, stream);

    // 1024 waves, one per l-row: 256 blocks x 256 threads (4 waves/block)
    const int threads = 256;
    const int blocks  = (L_ROWS * 64) / threads;  // 256
    edcc_kernel<<<blocks, threads, 0, stream>>>(projs, out);
}

// Round 3
// 159.314 us; speedup vs baseline: 1.0614x; 1.0614x over previous
//
#include <hip/hip_runtime.h>
#include <math.h>

// eDCC loss: reference reads only projs[0,127,:,:] and projs[0,29,:,:].
// For each l in [0,1024): P_i[l] = sum_s projs[127,l,s]*w[s],
//                         P_j[l] = sum_s projs[29 ,l,s]*w[s],
// w[s] = exp(sigma * s_grid[s] * SPACING), sigma = 0.013*tan(pi*98/128),
// s_grid[s] = (s - 127.5)*SPACING.
// out = sum_l (2/128)*|P_i - P_j|/(P_i + P_j)  (den != 0 guard), B=1 mean.
//
// R1 lesson: 1024 same-address atomicAdds serialized at ~160 ns each = ~164 us
// (matched the measured 169 us). This version: 256 waves x 4 rows, LDS
// block-reduce, 16 atomics total.
// R2: infra failure (container), same kernel resubmitted.

#define L_ROWS   1024
#define S_LEN    256
#define I_ROW    127
#define J_ROW    29
#define THREADS  1024            // 16 waves/block
#define BLOCKS   16              // 256 waves total, 4 rows each

__global__ __launch_bounds__(THREADS) void edcc_kernel(const float* __restrict__ projs,
                                                       float* __restrict__ out) {
    const int wid  = threadIdx.x >> 6;                 // wave in block [0,16)
    const int lane = threadIdx.x & 63;
    const int gw   = blockIdx.x * (THREADS / 64) + wid; // global wave [0,256)

    // Per-lane Laplace weights, computed once (double constants, cast late).
    const double sigma = 0.013 * tan((98.0 * (6.283185307179586 / 128.0)) * 0.5);
    float w[4];
#pragma unroll
    for (int c = 0; c < 4; ++c) {
        const double s_k = ((double)(lane * 4 + c) - 127.5) * 4.7952;
        w[c] = expf((float)(sigma * s_k * 4.7952));    // |arg| <= 34.6, f32-safe
    }

    float term_sum = 0.0f;
#pragma unroll
    for (int r = 0; r < 4; ++r) {
        const int l = gw + 256 * r;                    // 4 rows per wave
        const float* rowi = projs + ((size_t)(I_ROW * L_ROWS + l)) * S_LEN;
        const float* rowj = projs + ((size_t)(J_ROW * L_ROWS + l)) * S_LEN;
        const float4 vi = *reinterpret_cast<const float4*>(rowi + lane * 4);
        const float4 vj = *reinterpret_cast<const float4*>(rowj + lane * 4);

        float pi = fmaf(vi.x, w[0], fmaf(vi.y, w[1], fmaf(vi.z, w[2], vi.w * w[3])));
        float pj = fmaf(vj.x, w[0], fmaf(vj.y, w[1], fmaf(vj.z, w[2], vj.w * w[3])));

#pragma unroll
        for (int off = 32; off > 0; off >>= 1) {
            pi += __shfl_xor(pi, off);
            pj += __shfl_xor(pj, off);
        }
        const float den = pi + pj;
        if (den != 0.0f)
            term_sum += (2.0f / 128.0f) * fabsf(pi - pj) / den;
    }

    // Block reduction: one partial per wave -> LDS -> wave 0 -> 1 atomic/block.
    __shared__ float lds[THREADS / 64];
    if (lane == 0) lds[wid] = term_sum;
    __syncthreads();
    if (wid == 0) {
        float v = (lane < THREADS / 64) ? lds[lane] : 0.0f;
#pragma unroll
        for (int off = 32; off > 0; off >>= 1) v += __shfl_xor(v, off);
        if (lane == 0) atomicAdd(out, v);              // 16 atomics total
    }
}

extern "C" void kernel_launch(void* const* d_in, const int* in_sizes, int n_in,
                              void* d_out, int out_size, void* d_ws, size_t ws_size,
                              hipStream_t stream) {
    const float* projs = (const float*)d_in[0];
    float* out = (float*)d_out;

    // d_out is re-poisoned to 0xAA before every timed launch — zero it.
    hipMemsetAsync(out, 0, sizeof(float) * (size_t)out_size, stream);

    edcc_kernel<<<BLOCKS, THREADS, 0, stream>>>(projs, out);
}